// Round 1
// baseline (669.403 us; speedup 1.0000x reference)
//
#include <hip/hip_runtime.h>
#include <math.h>

#define ROW 2064   // 6*344 floats per obs row
#define OS  344

__device__ __constant__ int SRCMAP[13] = {108,109,127,128,110,111,129,130,112,113,133,131,132};

__device__ __forceinline__ float lrelu(float x, float s){ return x >= 0.f ? x : s*x; }
__device__ __forceinline__ float eluf(float x){ return x > 0.f ? x : expm1f(x); }

// ---------------- Kernel 1: ego-history MLP + lane MLP + road scalars ----------------
__global__ __launch_bounds__(512) void k_ego_lane(
    const float* __restrict__ obs,
    const float* __restrict__ Wself, const float* __restrict__ bself,
    const float* __restrict__ Wdyn,  const float* __restrict__ bdyn,
    const float* __restrict__ lW1, const float* __restrict__ lb1,
    const float* __restrict__ lW2, const float* __restrict__ lb2,
    float* __restrict__ comb, int Bn)
{
  __shared__ _Float16 sWself[15*128];
  __shared__ _Float16 sWdyn[128*64];
  __shared__ _Float16 sLW1[108*64];
  __shared__ _Float16 sLW2[64*64];
  __shared__ float sbself[128], sbdyn[64], slb1[64], slb2[64];
  __shared__ float shist[8][16];
  __shared__ float scur[8][136];
  __shared__ float x128[8][128];
  __shared__ float lhid[8][64];

  int tid = threadIdx.x;
  for (int i=tid;i<15*128;i+=512) sWself[i]=(_Float16)Wself[i];
  for (int i=tid;i<128*64;i+=512) sWdyn[i]=(_Float16)Wdyn[i];
  for (int i=tid;i<108*64;i+=512) sLW1[i]=(_Float16)lW1[i];
  for (int i=tid;i<64*64;i+=512)  sLW2[i]=(_Float16)lW2[i];
  if (tid<128) sbself[tid]=bself[tid];
  if (tid<64){ sbdyn[tid]=bdyn[tid]; slb1[tid]=lb1[tid]; slb2[tid]=lb2[tid]; }
  __syncthreads();

  int wave=tid>>6, lane=tid&63;
  for (int it=0; it<8; ++it){
    int e = blockIdx.x*64 + wave*8 + it;
    bool act = e < Bn;
    const float* row = obs + (long)e*ROW;
    if (act){
      if (lane<15){ int s=lane/3, k=lane-3*s; shist[wave][lane]=row[(s+1)*OS+234+k]; }
      for (int i=lane;i<134;i+=64) scur[wave][i]=row[5*OS+120+i];
    }
    __syncthreads();
    // ego: [15]@[15,128], double leaky(0.1) => negative side *0.01
    float a0=sbself[lane], a1=sbself[lane+64];
    #pragma unroll
    for (int k=0;k<15;++k){ float xv=shist[wave][k];
      a0 += xv*(float)sWself[k*128+lane]; a1 += xv*(float)sWself[k*128+64+lane]; }
    x128[wave][lane]    = a0>=0.f? a0 : 0.01f*a0;
    x128[wave][lane+64] = a1>=0.f? a1 : 0.01f*a1;
    __syncthreads();
    float ef=sbdyn[lane];
    #pragma unroll 4
    for (int k=0;k<128;++k) ef += x128[wave][k]*(float)sWdyn[k*64+lane];
    // lane MLP: [108]@[108,64] relu @[64,64] relu
    float l1=slb1[lane];
    #pragma unroll 4
    for (int k=0;k<108;++k) l1 += scur[wave][k]*(float)sLW1[k*64+lane];
    lhid[wave][lane] = fmaxf(l1,0.f);
    __syncthreads();
    float l2=slb2[lane];
    #pragma unroll 4
    for (int k=0;k<64;++k) l2 += lhid[wave][k]*(float)sLW2[k*64+lane];
    if (act){
      float* cr = comb + (long)e*272;
      cr[lane]     = ef;                  // ego_feat -> comb[0:64]
      cr[192+lane] = fmaxf(l2,0.f);       // lane     -> comb[192:256]
      if (lane<13) cr[256+lane] = scur[wave][SRCMAP[lane]];  // road+gen+exe
    }
    __syncthreads();
  }
}

// ---------------- Kernel 2: both GATs (star adjacency, collapsed form) ----------------
__global__ __launch_bounds__(512) void k_gat(
    const float* __restrict__ obs,
    const float* __restrict__ hWh, const float* __restrict__ ha1, const float* __restrict__ ha2,
    const float* __restrict__ hWo, const float* __restrict__ hao1, const float* __restrict__ hao2,
    const float* __restrict__ cWh, const float* __restrict__ ca1, const float* __restrict__ ca2,
    const float* __restrict__ cWo, const float* __restrict__ cao1, const float* __restrict__ cao2,
    float* __restrict__ comb, int Bn)
{
  __shared__ float sWh[2][144], sa1[2][48], sa2[2][48], sao1[2][64], sao2[2][64];
  __shared__ _Float16 sWo[2][48*64];
  __shared__ float scur[8][124];
  __shared__ float h[8][13*48];
  __shared__ float att[8][40];
  __shared__ float s2[8][40];
  __shared__ float s1[8][4];
  __shared__ float x20[8][48], x2X[8][48];

  int tid=threadIdx.x;
  for (int i=tid;i<144;i+=512){ sWh[0][i]=hWh[i]; sWh[1][i]=cWh[i]; }
  if (tid<48){ sa1[0][tid]=ha1[tid]; sa1[1][tid]=ca1[tid]; sa2[0][tid]=ha2[tid]; sa2[1][tid]=ca2[tid]; }
  if (tid<64){ sao1[0][tid]=hao1[tid]; sao1[1][tid]=cao1[tid]; sao2[0][tid]=hao2[tid]; sao2[1][tid]=cao2[tid]; }
  for (int i=tid;i<48*64;i+=512){ sWo[0][i]=(_Float16)hWo[i]; sWo[1][i]=(_Float16)cWo[i]; }
  __syncthreads();

  int wave=tid>>6, lane=tid&63;
  int head=lane>>4, c=lane&15;
  for (int it=0; it<8; ++it){
    int e = blockIdx.x*64 + wave*8 + it;
    bool act = e<Bn;
    const float* row = obs + (long)e*ROW + 5*OS;
    if (act){
      // 0..119: hdv+cav rows, 120..122: ego self[:3] (cur offset 234..236)
      for (int i=lane;i<123;i+=64) scur[wave][i] = (i<120)? row[i] : row[114+i];
    }
    __syncthreads();
    for (int g=0; g<2; ++g){
      int N = g? 9:13, foff = g? 72:0, coff = g? 128:64;
      const float* Wh=sWh[g]; const float* A1=sa1[g]; const float* A2=sa2[g];
      const float* AO1=sao1[g]; const float* AO2=sao2[g]; const _Float16* Wo=sWo[g];
      // h[n][head][c] = node_n(3) @ Wh[head][:,c]
      if (lane<48){
        float w0=Wh[head*48+c], w1=Wh[head*48+16+c], w2=Wh[head*48+32+c];
        for (int n=0;n<N;++n){
          float x0,x1,x2;
          if (n==0){ x0=scur[wave][120]; x1=scur[wave][121]; x2=scur[wave][122]; }
          else { int b0=foff+(n-1)*6; x0=scur[wave][b0]; x1=scur[wave][b0+1]; x2=scur[wave][b0+2]; }
          h[wave][n*48+lane] = x0*w0+x1*w1+x2*w2;
        }
      }
      __syncthreads();
      // attention-1 scores: s1 = a1.h0 per head ; s2[n] = a2.h_n per head
      if (lane<48){
        float a1w=A1[lane], a2w=A2[lane];
        for (int n=0;n<N;++n){
          float p=a2w*h[wave][n*48+lane];
          p += __shfl_xor(p,1); p += __shfl_xor(p,2); p += __shfl_xor(p,4); p += __shfl_xor(p,8);
          if (c==0) s2[wave][n*3+head]=p;
        }
        float q=a1w*h[wave][lane];
        q += __shfl_xor(q,1); q += __shfl_xor(q,2); q += __shfl_xor(q,4); q += __shfl_xor(q,8);
        if (c==0) s1[wave][head]=q;
      }
      __syncthreads();
      // softmax over N for ego row, per head (rows i>0 are one-hot on node 0)
      if (lane<3){
        float s1v=s1[wave][lane];
        float m=-1e30f;
        for (int n=0;n<N;++n){ float t=lrelu(s1v+s2[wave][n*3+lane],0.2f); m=fmaxf(m,t); }
        float sum=0.f;
        for (int n=0;n<N;++n){ float t=lrelu(s1v+s2[wave][n*3+lane],0.2f); float w=expf(t-m); att[wave][n*3+lane]=w; sum+=w; }
        float inv=1.f/sum;
        for (int n=0;n<N;++n) att[wave][n*3+lane]*=inv;
      }
      __syncthreads();
      // layer-1 outputs: ego row = elu(sum att*h) ; all other rows = elu(h0)
      if (lane<48){
        float acc=0.f;
        for (int n=0;n<N;++n) acc += att[wave][n*3+head]*h[wave][n*48+lane];
        x20[wave][lane]=eluf(acc);
        x2X[wave][lane]=eluf(h[wave][lane]);
      }
      __syncthreads();
      // ho0/hoX = x2 @ Wo ; attention-2 row 0 has 2 distinct scores (mult N-1)
      float acc0=0.f, accX=0.f;
      #pragma unroll 4
      for (int k=0;k<48;++k){ float w=(float)Wo[k*64+lane]; acc0+=x20[wave][k]*w; accX+=x2X[wave][k]*w; }
      float p1=acc0*AO1[lane], p2=acc0*AO2[lane], p3=accX*AO2[lane];
      #pragma unroll
      for (int ms=32;ms>=1;ms>>=1){ p1+=__shfl_xor(p1,ms); p2+=__shfl_xor(p2,ms); p3+=__shfl_xor(p3,ms); }
      float e00=lrelu(p1+p2,0.2f), e0X=lrelu(p1+p3,0.2f);
      float mm=fmaxf(e00,e0X);
      float w0=expf(e00-mm), wX=expf(e0X-mm);
      float den=w0+(float)(N-1)*wX;
      float v=(w0*acc0+(float)(N-1)*wX*accX)/den;
      if (act) comb[(long)e*272+coff+lane]=eluf(v);
      __syncthreads();
    }
  }
}

// ---------------- Kernel 3: comb head  relu(relu(comb@W1+b1)@W2+b2) ----------------
__global__ __launch_bounds__(512) void k_comb(
    const float* __restrict__ comb,
    const float* __restrict__ W1, const float* __restrict__ b1,
    const float* __restrict__ W2, const float* __restrict__ b2,
    float* __restrict__ out, int Bn)
{
  __shared__ _Float16 sW1[269*64];
  __shared__ _Float16 sW2[64*64];
  __shared__ float sb1[64], sb2[64];
  __shared__ float cc[8][272];
  __shared__ float chid[8][64];
  int tid=threadIdx.x;
  for (int i=tid;i<269*64;i+=512) sW1[i]=(_Float16)W1[i];
  for (int i=tid;i<64*64;i+=512)  sW2[i]=(_Float16)W2[i];
  if (tid<64){ sb1[tid]=b1[tid]; sb2[tid]=b2[tid]; }
  __syncthreads();
  int wave=tid>>6, lane=tid&63;
  for (int it=0;it<8;++it){
    int e=blockIdx.x*64+wave*8+it;
    bool act=e<Bn;
    const float* cr = comb + (long)e*272;
    if (act){ for (int i=lane;i<269;i+=64) cc[wave][i]=cr[i]; }
    __syncthreads();
    float acc=sb1[lane];
    #pragma unroll 4
    for (int k=0;k<269;++k) acc += cc[wave][k]*(float)sW1[k*64+lane];
    chid[wave][lane]=fmaxf(acc,0.f);
    __syncthreads();
    float o=sb2[lane];
    #pragma unroll 4
    for (int k=0;k<64;++k) o += chid[wave][k]*(float)sW2[k*64+lane];
    if (act) out[(long)e*64+lane]=fmaxf(o,0.f);
    __syncthreads();
  }
}

extern "C" void kernel_launch(void* const* d_in, const int* in_sizes, int n_in,
                              void* d_out, int out_size, void* d_ws, size_t ws_size,
                              hipStream_t stream)
{
  const float* obs  =(const float*)d_in[0];
  const float* Wself=(const float*)d_in[1];  const float* bself=(const float*)d_in[2];
  const float* Wdyn =(const float*)d_in[3];  const float* bdyn =(const float*)d_in[4];
  const float* hWh  =(const float*)d_in[5];  const float* ha1  =(const float*)d_in[6];
  const float* ha2  =(const float*)d_in[7];  const float* hWo  =(const float*)d_in[8];
  const float* hao1 =(const float*)d_in[9];  const float* hao2 =(const float*)d_in[10];
  const float* cWh  =(const float*)d_in[11]; const float* ca1  =(const float*)d_in[12];
  const float* ca2  =(const float*)d_in[13]; const float* cWo  =(const float*)d_in[14];
  const float* cao1 =(const float*)d_in[15]; const float* cao2 =(const float*)d_in[16];
  const float* lW1  =(const float*)d_in[17]; const float* lb1  =(const float*)d_in[18];
  const float* lW2  =(const float*)d_in[19]; const float* lb2  =(const float*)d_in[20];
  const float* cmW1 =(const float*)d_in[21]; const float* cmb1 =(const float*)d_in[22];
  const float* cmW2 =(const float*)d_in[23]; const float* cmb2 =(const float*)d_in[24];

  int Bn = in_sizes[0] / ROW;
  float* comb = (float*)d_ws;          // [Bn][272] fp32
  float* out  = (float*)d_out;
  int blocks = (Bn + 63)/64;

  k_ego_lane<<<blocks,512,0,stream>>>(obs,Wself,bself,Wdyn,bdyn,lW1,lb1,lW2,lb2,comb,Bn);
  k_gat<<<blocks,512,0,stream>>>(obs,hWh,ha1,ha2,hWo,hao1,hao2,cWh,ca1,ca2,cWo,cao1,cao2,comb,Bn);
  k_comb<<<blocks,512,0,stream>>>(comb,cmW1,cmb1,cmW2,cmb2,out,Bn);
}

// Round 2
// 661.991 us; speedup vs baseline: 1.0112x; 1.0112x over previous
//
#include <hip/hip_runtime.h>
#include <math.h>

#define ROW 2064   // 6*344 floats per obs row
#define OS  344

typedef _Float16 h2 __attribute__((ext_vector_type(2)));
typedef _Float16 h8 __attribute__((ext_vector_type(8)));

__device__ __constant__ int SRCMAP[13] = {108,109,127,128,110,111,129,130,112,113,133,131,132};

__device__ __forceinline__ float lrelu(float x, float s){ return x >= 0.f ? x : s*x; }
__device__ __forceinline__ float eluf(float x){ return x > 0.f ? x : expm1f(x); }

#if __has_builtin(__builtin_amdgcn_fdot2)
#define FDOT2(a,b,c) __builtin_amdgcn_fdot2((a),(b),(c),false)
#else
__device__ __forceinline__ float fdot2_fallback(h2 a, h2 b, float c){
  return c + (float)a.x*(float)b.x + (float)a.y*(float)b.y; }
#define FDOT2 fdot2_fallback
#endif

__device__ __forceinline__ float dot8f(h8 x, h2 w0, h2 w1, h2 w2, h2 w3, float acc){
  union{h8 v; h2 p[4];} u; u.v = x;
  acc = FDOT2(u.p[0], w0, acc); acc = FDOT2(u.p[1], w1, acc);
  acc = FDOT2(u.p[2], w2, acc); acc = FDOT2(u.p[3], w3, acc);
  return acc;
}

// ============ Kernel 1: ego-history MLP + lane MLP + road scalars ============
// 256 thr = 4 waves; wave handles 8 examples; 2 iters -> 64 ex/block.
// Weights col-major fp16, odd h2-word stride (conflict-free b32 reads).
__global__ __launch_bounds__(256) void k_ego_lane(
    const float* __restrict__ obs,
    const float* __restrict__ Wself, const float* __restrict__ bself,
    const float* __restrict__ Wdyn,  const float* __restrict__ bdyn,
    const float* __restrict__ lW1, const float* __restrict__ lb1,
    const float* __restrict__ lW2, const float* __restrict__ lb2,
    _Float16* __restrict__ comb, int Bn)
{
  __shared__ h2 sWs[128*9];    // Wself [col][k] stride 18 f16 (k<15, pad 16..17=0)
  __shared__ h2 sWd[64*65];    // Wdyn stride 130 (k<128)
  __shared__ h2 sL1[64*57];    // lW1 stride 114 (k<108, pad->112)
  __shared__ h2 sL2[64*33];    // lW2 stride 66 (k<64)
  __shared__ float sbs[128], sbd[64], sB1[64], sB2[64];
  __shared__ h8 shist[4][8][2];    // [wave][ex][16 f16]
  __shared__ h8 scur[4][8][14];    // [wave][ex][112 f16] lane input
  __shared__ h8 sxx[4][8][16];     // [wave][ex][128 f16] x128; reused for lhid(64)

  int tid = threadIdx.x;
  { h2 z; z.x=(_Float16)0.f; z.y=(_Float16)0.f;
    for (int i=tid;i<128*9;i+=256) sWs[i]=z;
    for (int i=tid;i<64*65;i+=256) sWd[i]=z;
    for (int i=tid;i<64*57;i+=256) sL1[i]=z;
    for (int i=tid;i<64*33;i+=256) sL2[i]=z;
  }
  __syncthreads();
  { _Float16* w;
    w=(_Float16*)sWs; for (int i=tid;i<15*128;i+=256){int k=i>>7,c=i&127; w[c*18+k]=(_Float16)Wself[i];}
    w=(_Float16*)sWd; for (int i=tid;i<128*64;i+=256){int k=i>>6,c=i&63; w[c*130+k]=(_Float16)Wdyn[i];}
    w=(_Float16*)sL1; for (int i=tid;i<108*64;i+=256){int k=i>>6,c=i&63; w[c*114+k]=(_Float16)lW1[i];}
    w=(_Float16*)sL2; for (int i=tid;i<64*64;i+=256){int k=i>>6,c=i&63; w[c*66+k]=(_Float16)lW2[i];}
  }
  if (tid<128) sbs[tid]=bself[tid];
  if (tid<64){ sbd[tid]=bdyn[tid]; sB1[tid]=lb1[tid]; sB2[tid]=lb2[tid]; }
  __syncthreads();

  int wv=tid>>6, lane=tid&63;
  for (int it=0; it<2; ++it){
    int e0 = blockIdx.x*64 + it*32 + wv*8;
    // ---- stage activations (fp16) ----
    _Float16* sh = (_Float16*)&shist[wv][0][0];
    for (int i=lane;i<128;i+=64){ int e=i>>4, j=i&15; int ge=e0+e; float v=0.f;
      if (j<15 && ge<Bn) v = obs[(long)ge*ROW + (1+j/3)*OS + 234 + (j%3)];
      sh[e*16+j]=(_Float16)v; }
    _Float16* scu = (_Float16*)&scur[wv][0][0];
    for (int i=lane;i<8*112;i+=64){ int e=i/112, j=i-112*e; int ge=e0+e; float v=0.f;
      if (j<108 && ge<Bn) v = obs[(long)ge*ROW + 5*OS + 120 + j];
      scu[e*112+j]=(_Float16)v; }
    __syncthreads();

    // ---- ego layer1: [15]->[128], double leaky(0.1) ----
    float a0[8], a1[8];
    { float b0=sbs[lane], b1=sbs[lane+64];
      #pragma unroll
      for (int e=0;e<8;++e){ a0[e]=b0; a1[e]=b1; }
      #pragma unroll
      for (int c=0;c<2;++c){
        const h2* wp0=&sWs[lane*9+4*c]; const h2* wp1=&sWs[(lane+64)*9+4*c];
        h2 u0=wp0[0],u1=wp0[1],u2=wp0[2],u3=wp0[3];
        h2 v0=wp1[0],v1=wp1[1],v2=wp1[2],v3=wp1[3];
        #pragma unroll
        for (int e=0;e<8;++e){ h8 x=shist[wv][e][c];
          a0[e]=dot8f(x,u0,u1,u2,u3,a0[e]);
          a1[e]=dot8f(x,v0,v1,v2,v3,a1[e]); }
      }
      _Float16* sx=(_Float16*)&sxx[wv][0][0];
      #pragma unroll
      for (int e=0;e<8;++e){
        float x0=a0[e]; x0 = x0>=0.f? x0 : 0.01f*x0;
        float x1=a1[e]; x1 = x1>=0.f? x1 : 0.01f*x1;
        sx[e*128+lane]=(_Float16)x0; sx[e*128+64+lane]=(_Float16)x1; }
    }
    __syncthreads();

    // ---- dyn: [128]->[64] ----
    float ef[8];
    { float bb=sbd[lane];
      #pragma unroll
      for (int e=0;e<8;++e) ef[e]=bb;
      #pragma unroll 4
      for (int c=0;c<16;++c){
        const h2* wp=&sWd[lane*65+4*c];
        h2 w0=wp[0],w1=wp[1],w2=wp[2],w3=wp[3];
        #pragma unroll
        for (int e=0;e<8;++e){ h8 x=sxx[wv][e][c]; ef[e]=dot8f(x,w0,w1,w2,w3,ef[e]); }
      }
    }
    // ---- lane1: [108]->[64] relu ----
    float l1[8];
    { float bb=sB1[lane];
      #pragma unroll
      for (int e=0;e<8;++e) l1[e]=bb;
      #pragma unroll 4
      for (int c=0;c<14;++c){
        const h2* wp=&sL1[lane*57+4*c];
        h2 w0=wp[0],w1=wp[1],w2=wp[2],w3=wp[3];
        #pragma unroll
        for (int e=0;e<8;++e){ h8 x=scur[wv][e][c]; l1[e]=dot8f(x,w0,w1,w2,w3,l1[e]); }
      }
      _Float16* sx=(_Float16*)&sxx[wv][0][0];   // overwrite x128[0:64] with lhid (after dyn reads: program order per wave)
      #pragma unroll
      for (int e=0;e<8;++e) sx[e*128+lane]=(_Float16)fmaxf(l1[e],0.f);
    }
    __syncthreads();

    // ---- lane2: [64]->[64] relu ----
    float l2[8];
    { float bb=sB2[lane];
      #pragma unroll
      for (int e=0;e<8;++e) l2[e]=bb;
      #pragma unroll
      for (int c=0;c<8;++c){
        const h2* wp=&sL2[lane*33+4*c];
        h2 w0=wp[0],w1=wp[1],w2=wp[2],w3=wp[3];
        #pragma unroll
        for (int e=0;e<8;++e){ h8 x=sxx[wv][e][c]; l2[e]=dot8f(x,w0,w1,w2,w3,l2[e]); }
      }
    }
    // ---- write outputs ----
    #pragma unroll
    for (int e=0;e<8;++e){ int ge=e0+e;
      if (ge<Bn){
        comb[(long)ge*272+lane]=(_Float16)ef[e];
        comb[(long)ge*272+192+lane]=(_Float16)fmaxf(l2[e],0.f);
      } }
    for (int i=lane;i<104;i+=64){ int e=i/13, j=i-13*e; int ge=e0+e;
      if (ge<Bn) comb[(long)ge*272+256+j]=(_Float16)obs[(long)ge*ROW+5*OS+120+SRCMAP[j]]; }
    __syncthreads();
  }
}

// ============ Kernel 2: both GATs (star adjacency, algebraically collapsed) ============
// 512 thr = 8 waves x 8 examples = 64 ex/block.
__global__ __launch_bounds__(512) void k_gat(
    const float* __restrict__ obs,
    const float* __restrict__ hWh, const float* __restrict__ ha1, const float* __restrict__ ha2,
    const float* __restrict__ hWo, const float* __restrict__ hao1, const float* __restrict__ hao2,
    const float* __restrict__ cWh, const float* __restrict__ ca1, const float* __restrict__ ca2,
    const float* __restrict__ cWo, const float* __restrict__ cao1, const float* __restrict__ cao2,
    _Float16* __restrict__ comb, int Bn)
{
  __shared__ float sWh[2][144];        // [g][h*48+f*16+o]
  __shared__ float su[2][2][3][3];     // [g][a1/a2][h][f] = Wh^T a
  __shared__ float sao[2][2][64];
  __shared__ h2 sWo[2][64*25];         // col-major stride 50 f16 (k<48)
  __shared__ h8 xs[8][8][8];           // [wave][ex][64 f16]: x0(3), hdv 12x3, cav 8x3
  __shared__ float sc[8][8][40];       // scores -> att
  __shared__ float xagg[8][8][12];     // [h*3+f]
  __shared__ h8 x20s[8][8][6], x2Xs[8][8][6];  // 48 f16 each

  int tid=threadIdx.x;
  for (int i=tid;i<144;i+=512){ sWh[0][i]=hWh[i]; sWh[1][i]=cWh[i]; }
  if (tid<64){ sao[0][0][tid]=hao1[tid]; sao[0][1][tid]=hao2[tid];
               sao[1][0][tid]=cao1[tid]; sao[1][1][tid]=cao2[tid]; }
  { h2 z; z.x=(_Float16)0.f; z.y=(_Float16)0.f;
    for (int i=tid;i<2*64*25;i+=512) ((h2*)sWo)[i]=z; }
  __syncthreads();
  { _Float16* q=(_Float16*)&sWo[0][0];
    for (int i=tid;i<48*64;i+=512){int k=i>>6,c=i&63;
      q[c*50+k]=(_Float16)hWo[i]; q[64*50+c*50+k]=(_Float16)cWo[i]; } }
  if (tid<36){ int t=tid; int g=t/18, w=(t%18)/9, h=(t%9)/3, f=t%3;
    const float* A  = g ? (w? ca2:ca1) : (w? ha2:ha1);
    const float* WH = g ? cWh : hWh;
    float s=0.f;
    for (int o=0;o<16;++o) s += WH[h*48+f*16+o]*A[h*16+o];
    su[g][w][h][f]=s; }
  __syncthreads();

  int wv=tid>>6, lane=tid&63;
  int e0 = blockIdx.x*64 + wv*8;
  _Float16* x16=(_Float16*)&xs[wv][0][0];
  for (int p=0;p<8;++p){ int ge=e0+p; int j=lane; float v=0.f;
    if (ge<Bn){ const float* row=obs+(long)ge*ROW+5*OS;
      if (j<3) v=row[234+j];
      else if (j<39){ int k=(j-3)/3, d=(j-3)%3; v=row[k*6+d]; }
      else if (j<63){ int k=(j-39)/3, d=(j-39)%3; v=row[72+k*6+d]; }
    }
    x16[p*64+j]=(_Float16)v; }
  __syncthreads();

  int e=lane>>3, h=lane&7;
  for (int g=0; g<2; ++g){
    int N = g? 9:13; int xoff = g? 39:3; int coff = g? 128:64;
    // ---- attention-1 scores + softmax (ego row only; other rows collapse) ----
    if (h<3){
      float s1=0.f;
      #pragma unroll
      for (int f=0;f<3;++f) s1 += su[g][0][h][f]*(float)x16[e*64+f];
      float mx=-1e30f;
      for (int n=0;n<N;++n){ float s2=0.f; int b = n? (xoff+(n-1)*3) : 0;
        #pragma unroll
        for (int f=0;f<3;++f) s2 += su[g][1][h][f]*(float)x16[e*64+b+f];
        float ev=lrelu(s1+s2,0.2f); sc[wv][e][n*3+h]=ev; mx=fmaxf(mx,ev); }
      float sum=0.f;
      for (int n=0;n<N;++n){ float w=__expf(sc[wv][e][n*3+h]-mx); sc[wv][e][n*3+h]=w; sum+=w; }
      float inv=1.f/sum;
      for (int n=0;n<N;++n) sc[wv][e][n*3+h]*=inv;
      // ---- aggregate x (3-dim) with att ----
      float g0=0.f,g1=0.f,g2=0.f;
      for (int n=0;n<N;++n){ float a=sc[wv][e][n*3+h]; int b = n? (xoff+(n-1)*3) : 0;
        g0+=a*(float)x16[e*64+b]; g1+=a*(float)x16[e*64+b+1]; g2+=a*(float)x16[e*64+b+2]; }
      xagg[wv][e][h*3+0]=g0; xagg[wv][e][h*3+1]=g1; xagg[wv][e][h*3+2]=g2;
    }
    __syncthreads();
    // ---- x20 = elu(xagg @ Wh), x2X = elu(x0 @ Wh) : 8ex x 48 in 6 passes ----
    { _Float16* p20=(_Float16*)&x20s[wv][0][0]; _Float16* p2X=(_Float16*)&x2Xs[wv][0][0];
      int ee=lane>>3, jb=lane&7;
      #pragma unroll
      for (int p=0;p<6;++p){ int jj=jb+8*p; int hh=jj>>4, oo=jj&15;
        const float* WH=&sWh[g][hh*48];
        float w0=WH[oo], w1=WH[16+oo], w2=WH[32+oo];
        float v0 = xagg[wv][ee][hh*3+0]*w0 + xagg[wv][ee][hh*3+1]*w1 + xagg[wv][ee][hh*3+2]*w2;
        float vX = (float)x16[ee*64+0]*w0 + (float)x16[ee*64+1]*w1 + (float)x16[ee*64+2]*w2;
        p20[ee*48+jj]=(_Float16)eluf(v0); p2X[ee*48+jj]=(_Float16)eluf(vX); }
    }
    __syncthreads();
    // ---- ho = x2 @ Wo (K=48) for ego row and generic row ----
    float acc0[8], accX[8];
    #pragma unroll
    for (int e2=0;e2<8;++e2){ acc0[e2]=0.f; accX[e2]=0.f; }
    #pragma unroll
    for (int c=0;c<6;++c){
      const h2* wp=&sWo[g][lane*25+4*c];
      h2 w0=wp[0],w1=wp[1],w2=wp[2],w3=wp[3];
      #pragma unroll
      for (int e2=0;e2<8;++e2){
        h8 xa=x20s[wv][e2][c]; acc0[e2]=dot8f(xa,w0,w1,w2,w3,acc0[e2]);
        h8 xb=x2Xs[wv][e2][c]; accX[e2]=dot8f(xb,w0,w1,w2,w3,accX[e2]); }
    }
    // ---- attention-2 (2 distinct scores, multiplicity N-1) + out ----
    float AO1=sao[g][0][lane], AO2=sao[g][1][lane];
    #pragma unroll
    for (int e2=0;e2<8;++e2){
      float p1=acc0[e2]*AO1, p2=acc0[e2]*AO2, p3=accX[e2]*AO2;
      #pragma unroll
      for (int ms=32;ms>=1;ms>>=1){ p1+=__shfl_xor(p1,ms); p2+=__shfl_xor(p2,ms); p3+=__shfl_xor(p3,ms); }
      float e00=lrelu(p1+p2,0.2f), e0X=lrelu(p1+p3,0.2f);
      float mm=fmaxf(e00,e0X);
      float w0=__expf(e00-mm), wX=__expf(e0X-mm);
      float den=w0+(float)(N-1)*wX;
      float v=(w0*acc0[e2]+(float)(N-1)*wX*accX[e2])/den;
      int ge=e0+e2;
      if (ge<Bn) comb[(long)ge*272+coff+lane]=(_Float16)eluf(v);
    }
    __syncthreads();
  }
}

// ============ Kernel 3: comb head relu(relu(comb@W1+b1)@W2+b2) ============
__global__ __launch_bounds__(256) void k_comb(
    const _Float16* __restrict__ comb,
    const float* __restrict__ W1, const float* __restrict__ b1,
    const float* __restrict__ W2, const float* __restrict__ b2,
    float* __restrict__ out, int Bn)
{
  __shared__ h2 sW1[64*137];   // stride 274 f16 (k<269, pad->272)
  __shared__ h2 sW2[64*33];
  __shared__ float sb1[64], sb2[64];
  __shared__ h8 cc[4][8][34];  // [wave][ex][272 f16]; [0:64] reused for chid

  int tid=threadIdx.x;
  { h2 z; z.x=(_Float16)0.f; z.y=(_Float16)0.f;
    for (int i=tid;i<64*137;i+=256) sW1[i]=z;
    for (int i=tid;i<64*33;i+=256) sW2[i]=z; }
  __syncthreads();
  { _Float16* w;
    w=(_Float16*)sW1; for (int i=tid;i<269*64;i+=256){int k=i>>6,c=i&63; w[c*274+k]=(_Float16)W1[i];}
    w=(_Float16*)sW2; for (int i=tid;i<64*64;i+=256){int k=i>>6,c=i&63; w[c*66+k]=(_Float16)W2[i];} }
  if (tid<64){ sb1[tid]=b1[tid]; sb2[tid]=b2[tid]; }
  __syncthreads();

  int wv=tid>>6, lane=tid&63;
  for (int it=0; it<2; ++it){
    int e0 = blockIdx.x*64 + it*32 + wv*8;
    _Float16* c16=(_Float16*)&cc[wv][0][0];
    for (int i=lane;i<8*272;i+=64){ int e=i/272, j=i-272*e; int ge=e0+e;
      _Float16 v=(_Float16)0.f;
      if (j<269 && ge<Bn) v=comb[(long)ge*272+j];
      c16[e*272+j]=v; }
    __syncthreads();
    float h1[8];
    { float bb=sb1[lane];
      #pragma unroll
      for (int e=0;e<8;++e) h1[e]=bb;
      #pragma unroll 2
      for (int c=0;c<34;++c){
        const h2* wp=&sW1[lane*137+4*c];
        h2 w0=wp[0],w1=wp[1],w2=wp[2],w3=wp[3];
        #pragma unroll
        for (int e=0;e<8;++e){ h8 x=cc[wv][e][c]; h1[e]=dot8f(x,w0,w1,w2,w3,h1[e]); }
      }
      #pragma unroll
      for (int e=0;e<8;++e) c16[e*272+lane]=(_Float16)fmaxf(h1[e],0.f);   // chid overwrites cc[0:64]
    }
    __syncthreads();
    float o[8];
    { float bb=sb2[lane];
      #pragma unroll
      for (int e=0;e<8;++e) o[e]=bb;
      #pragma unroll
      for (int c=0;c<8;++c){
        const h2* wp=&sW2[lane*33+4*c];
        h2 w0=wp[0],w1=wp[1],w2=wp[2],w3=wp[3];
        #pragma unroll
        for (int e=0;e<8;++e){ h8 x=cc[wv][e][c]; o[e]=dot8f(x,w0,w1,w2,w3,o[e]); }
      }
    }
    #pragma unroll
    for (int e=0;e<8;++e){ int ge=e0+e;
      if (ge<Bn) out[(long)ge*64+lane]=fmaxf(o[e],0.f); }
    __syncthreads();
  }
}

extern "C" void kernel_launch(void* const* d_in, const int* in_sizes, int n_in,
                              void* d_out, int out_size, void* d_ws, size_t ws_size,
                              hipStream_t stream)
{
  const float* obs  =(const float*)d_in[0];
  const float* Wself=(const float*)d_in[1];  const float* bself=(const float*)d_in[2];
  const float* Wdyn =(const float*)d_in[3];  const float* bdyn =(const float*)d_in[4];
  const float* hWh  =(const float*)d_in[5];  const float* ha1  =(const float*)d_in[6];
  const float* ha2  =(const float*)d_in[7];  const float* hWo  =(const float*)d_in[8];
  const float* hao1 =(const float*)d_in[9];  const float* hao2 =(const float*)d_in[10];
  const float* cWh  =(const float*)d_in[11]; const float* ca1  =(const float*)d_in[12];
  const float* ca2  =(const float*)d_in[13]; const float* cWo  =(const float*)d_in[14];
  const float* cao1 =(const float*)d_in[15]; const float* cao2 =(const float*)d_in[16];
  const float* lW1  =(const float*)d_in[17]; const float* lb1  =(const float*)d_in[18];
  const float* lW2  =(const float*)d_in[19]; const float* lb2  =(const float*)d_in[20];
  const float* cmW1 =(const float*)d_in[21]; const float* cmb1 =(const float*)d_in[22];
  const float* cmW2 =(const float*)d_in[23]; const float* cmb2 =(const float*)d_in[24];

  int Bn = in_sizes[0] / ROW;
  _Float16* comb = (_Float16*)d_ws;   // [Bn][272] fp16
  float* out = (float*)d_out;
  int blocks = (Bn + 63)/64;

  k_ego_lane<<<blocks,256,0,stream>>>(obs,Wself,bself,Wdyn,bdyn,lW1,lb1,lW2,lb2,comb,Bn);
  k_gat<<<blocks,512,0,stream>>>(obs,hWh,ha1,ha2,hWo,hao1,hao2,cWh,ca1,ca2,cWo,cao1,cao2,comb,Bn);
  k_comb<<<blocks,256,0,stream>>>(comb,cmW1,cmb1,cmW2,cmb2,out,Bn);
}

// Round 3
// 636.547 us; speedup vs baseline: 1.0516x; 1.0400x over previous
//
#include <hip/hip_runtime.h>
#include <math.h>

#define ROW 2064   // 6*344 floats per obs row
#define OS  344

typedef _Float16 h2 __attribute__((ext_vector_type(2)));
typedef _Float16 h8 __attribute__((ext_vector_type(8)));

// fp16 weight blob layout (offsets in f16 units). Rows are [j][K] with K padded
// to a multiple of 8 and zero rows baked in; all row strides are 16B multiples
// except WHX (read scalar-only).
#define OFF_EGO 0        // 128 x 24   (k: 4 hist float4 slots x4 + span[232..240))
#define OFF_DYN 3072     // 64 x 128
#define OFF_L1  11264    // 64 x 112   (k: span[120..232), zeros at 228..231)
#define OFF_L2  18432    // 64 x 64
#define OFF_WHX 22528    // 2 x 48 x 4 (k: 3 + zero)
#define OFF_WO  22912    // 2 x 64 x 48
#define OFF_W1  29056    // 64 x 288   (k: ef64, hdv64, cav64, lane64, span[224..256))
#define OFF_W2  47488    // 64 x 64
#define WT_F16  51584
// fp32 section (float offsets from (float*)(wt + WT_F16))
#define FB_BSELF 0
#define FB_BDYN 128
#define FB_LB1 192
#define FB_LB2 256
#define FB_CB1 320
#define FB_CB2 384
#define FB_SU  448   // [g][w][h][f] : 36
#define FB_AO  484   // [g][w][64]   : 256
#define FS_TOT 740

union U4 { uint4 q; h2 p[8]; };
union U1 { uint u; h2 h; };

__device__ __forceinline__ float fd(h2 a, h2 b, float c){
#if __has_builtin(__builtin_amdgcn_fdot2)
  return __builtin_amdgcn_fdot2(a,b,c,false);
#else
  return c + (float)a.x*(float)b.x + (float)a.y*(float)b.y;
#endif
}
__device__ __forceinline__ float lrelu(float x,float s){ return x>=0.f? x : s*x; }
__device__ __forceinline__ float eluf(float x){ return x>0.f? x : expm1f(x); }
__device__ __forceinline__ uint packh2(float a,float b){ U1 u; u.h=(h2){(_Float16)a,(_Float16)b}; return u.u; }

__device__ __forceinline__ int span_to_comb(int sp){
  switch(sp){ case 228: return 256; case 229: return 257; case 230: return 260; case 231: return 261;
    case 232: return 264; case 233: return 265; case 247: return 258; case 248: return 259;
    case 249: return 262; case 250: return 263; case 251: return 267; case 252: return 268;
    case 253: return 266; default: return -1; }
}

// ======================= prologue: weight repack fp32 -> fp16 blob =======================
__global__ void k_prep(const float* __restrict__ Wself, const float* __restrict__ Wdyn,
                       const float* __restrict__ lW1, const float* __restrict__ lW2,
                       const float* __restrict__ hWh, const float* __restrict__ cWh,
                       const float* __restrict__ hWo, const float* __restrict__ cWo,
                       const float* __restrict__ ha1, const float* __restrict__ ha2,
                       const float* __restrict__ ca1, const float* __restrict__ ca2,
                       const float* __restrict__ hao1, const float* __restrict__ hao2,
                       const float* __restrict__ cao1, const float* __restrict__ cao2,
                       const float* __restrict__ bself, const float* __restrict__ bdyn,
                       const float* __restrict__ lb1, const float* __restrict__ lb2,
                       const float* __restrict__ cb1, const float* __restrict__ cb2,
                       _Float16* __restrict__ wt)
{
  int gid = blockIdx.x*blockDim.x + threadIdx.x;
  int nth = gridDim.x*blockDim.x;
  for (int idx = gid; idx < WT_F16; idx += nth){
    float v = 0.f;
    if (idx < OFF_DYN){ int l=idx; int j=l/24, k=l%24;
      if (k<16){ int s=k>>2, c=k&3; if (c<3) v = Wself[(s*3+c)*128 + j]; }
      else { int sp = 232 + (k-16); if (sp>=234 && sp<=236) v = Wself[(12+(sp-234))*128 + j]; }
    } else if (idx < OFF_L1){ int l=idx-OFF_DYN; int j=l>>7, k=l&127; v = Wdyn[k*64+j]; }
    else if (idx < OFF_L2){ int l=idx-OFF_L1; int j=l/112, k=l%112; if (k<108) v = lW1[k*64+j]; }
    else if (idx < OFF_WHX){ int l=idx-OFF_L2; int j=l>>6, k=l&63; v = lW2[k*64+j]; }
    else if (idx < OFF_WO){ int l=idx-OFF_WHX; int g=l/192; l-=g*192; int j=l>>2, k=l&3;
      const float* Wh = g? cWh : hWh; int hh=j>>4, o=j&15; if (k<3) v = Wh[hh*48 + k*16 + o]; }
    else if (idx < OFF_W1){ int l=idx-OFF_WO; int g=l/3072; l-=g*3072; int j=l/48, k=l%48;
      const float* Wo = g? cWo : hWo; v = Wo[k*64+j]; }
    else if (idx < OFF_W2){ int l=idx-OFF_W1; int j=l/288, k=l%288; const float* W1=lW1; (void)W1;
      if (k<256) v = 0.f, v = 0.f; // placeholder replaced below
      if (k<256){ v = 0.f; }
      // real mapping:
      if (k<256) v = 0.f;
      {
        int r;
        if (k<256) r = k;
        else r = span_to_comb(224 + (k-256));
        if (r>=0) v = 0.f; // set below with cmW1 via alias trick not available -> handled in second pass
      }
      // NOTE: cmW1/cmW2 are passed through lW1-style params? They are not; see k_prep2.
      v = 0.f; // W1 filled by k_prep2
    }
    else { v = 0.f; } // W2 filled by k_prep2
    if (idx < OFF_W1) wt[idx] = (_Float16)v;
  }
  // fp32 section
  float* fs = (float*)(wt + WT_F16);
  for (int i = gid; i < FS_TOT; i += nth){
    float v=0.f;
    if (i<128) v = bself[i];
    else if (i<192) v = bdyn[i-128];
    else if (i<256) v = lb1[i-192];
    else if (i<320) v = lb2[i-256];
    else if (i<384) v = cb1[i-320];
    else if (i<448) v = cb2[i-384];
    else if (i<484){ int t=i-448; int g=t/18, w=(t%18)/9, hh=(t%9)/3, f=t%3;
      const float* A = g? (w? ca2:ca1) : (w? ha2:ha1);
      const float* WH = g? cWh : hWh; v=0.f;
      for (int o=0;o<16;++o) v += WH[hh*48+f*16+o]*A[hh*16+o]; }
    else { int t=i-484; int g=t>>7, w=(t>>6)&1, j=t&63;
      const float* A = g? (w?cao2:cao1) : (w?hao2:hao1); v = A[j]; }
    fs[i]=v;
  }
}

// second prologue for comb W1/W2 (kept separate to stay under kernel-arg pressure)
__global__ void k_prep2(const float* __restrict__ cmW1, const float* __restrict__ cmW2,
                        _Float16* __restrict__ wt)
{
  int gid = blockIdx.x*blockDim.x + threadIdx.x;
  int nth = gridDim.x*blockDim.x;
  for (int idx = gid + OFF_W1; idx < WT_F16; idx += nth){
    float v = 0.f;
    if (idx < OFF_W2){ int l=idx-OFF_W1; int j=l/288, k=l%288;
      int r = (k<256) ? k : span_to_comb(224 + (k-256));
      if (r>=0) v = cmW1[r*64 + j];
    } else { int l=idx-OFF_W2; int j=l>>6, k=l&63; v = cmW2[k*64+j]; }
    wt[idx] = (_Float16)v;
  }
}

// ======================= GEMM passes (32 wave-uniform output cols per call) =======================
__device__ __forceinline__ float dot8u(uint a,uint b,uint c,uint d, const U4& q, float t){
  U1 u; u.u=a; t=fd(u.h,q.p[0],t); u.u=b; t=fd(u.h,q.p[1],t);
  u.u=c; t=fd(u.h,q.p[2],t); u.u=d; t=fd(u.h,q.p[3],t); return t;
}

// x from registers (C chunks of 4 uints)
__device__ __forceinline__ void gpassR(float acc[32], const uint* xu,
    const _Float16* __restrict__ wt, long wbase, int KP, int C){
  #pragma unroll
  for (int c=0;c<C;++c){
    uint a=xu[4*c], b=xu[4*c+1], cc=xu[4*c+2], d=xu[4*c+3];
    #pragma unroll
    for (int j=0;j<32;++j){
      U4 q = *(const U4*)(wt + wbase + (long)j*KP + (long)c*8);
      acc[j] = dot8u(a,b,cc,d,q,acc[j]);
    }
  }
}

// x from LDS row (per-lane private), C chunks
__device__ __forceinline__ void gpassL(float acc[32], const _Float16* xrow,
    const _Float16* __restrict__ wt, long wbase, int KP, int C){
  #pragma unroll 2
  for (int c=0;c<C;++c){
    union{h8 v; uint u[4];} x; x.v = *(const h8*)(xrow + c*8);
    #pragma unroll
    for (int j=0;j<32;++j){
      U4 q = *(const U4*)(wt + wbase + (long)j*KP + (long)c*8);
      acc[j] = dot8u(x.u[0],x.u[1],x.u[2],x.u[3],q,acc[j]);
    }
  }
}

// dual-x shared-weight variant (GAT ego + generic branch)
__device__ __forceinline__ void gpassL2(float a0[32], float a1[32],
    const _Float16* r0, const _Float16* r1,
    const _Float16* __restrict__ wt, long wbase, int KP, int C){
  #pragma unroll 2
  for (int c=0;c<C;++c){
    union{h8 v; uint u[4];} x0, x1; x0.v = *(const h8*)(r0 + c*8); x1.v = *(const h8*)(r1 + c*8);
    #pragma unroll
    for (int j=0;j<32;++j){
      U4 q = *(const U4*)(wt + wbase + (long)j*KP + (long)c*8);
      a0[j] = dot8u(x0.u[0],x0.u[1],x0.u[2],x0.u[3],q,a0[j]);
      a1[j] = dot8u(x1.u[0],x1.u[1],x1.u[2],x1.u[3],q,a1[j]);
    }
  }
}

// ======================= main fused kernel =======================
// block = 128 threads = 2 waves; wave w handles output-col half [32w,..) (wave-uniform
// -> weights stream via s_load); lane = example (64 ex per block).
__global__ __launch_bounds__(128,1) void k_main(const float* __restrict__ obs,
    const _Float16* __restrict__ wt, float* __restrict__ out, int Bn)
{
  __shared__ __align__(16) _Float16 sl[64*264];   // input span, per-ex rows (254 used)
  __shared__ __align__(16) _Float16 xa[64*136];   // x128 exchange / GAT x20,x2X scratch
  __shared__ __align__(16) _Float16 pb[64*72];    // 64-wide piece exchange
  __shared__ float pp[64*8];                      // att2 partial dots

  const float* fs = (const float*)(wt + WT_F16);
  int wj   = __builtin_amdgcn_readfirstlane((int)(threadIdx.x >> 6));
  int lane = threadIdx.x & 63;
  int jb   = 32*wj;
  int e0   = blockIdx.x*64;
  int ge   = e0 + lane; int gec = ge < Bn ? ge : Bn-1;

  // ---- stage: coalesced span load [5*OS, 5*OS+256) per example ----
  for (int t=wj; t<64; t+=2){
    int gx = e0 + t; if (gx >= Bn) gx = Bn-1;
    const float4* src = (const float4*)(obs + (long)gx*ROW + 5*OS);
    float4 v = src[lane];
    uint2 w; w.x = packh2(v.x,v.y); w.y = packh2(v.z,v.w);
    *(uint2*)&sl[t*264 + lane*4] = w;
  }
  // hist (own example): 4 steps x (float2+float2)
  const float* myrow = obs + (long)gec*ROW;
  uint hu[8];
  #pragma unroll
  for (int s=0;s<4;++s){
    float2 ab = *(const float2*)(myrow + (s+1)*OS + 234);
    float2 cd = *(const float2*)(myrow + (s+1)*OS + 236);
    hu[2*s] = packh2(ab.x,ab.y); hu[2*s+1] = packh2(cd.x,cd.y);
  }
  __syncthreads();                                              // S1

  const _Float16* slp = sl + lane*264;
  _Float16* xrow = xa + lane*136;
  _Float16* pbrow = pb + lane*72;

  // ---- ego: [24]->[128], double leaky(0.1); wave half = 64 cols in 2 passes ----
  uint xe[12];
  { union{h8 v; uint u[4];} t29; t29.v = *(const h8*)(slp + 232);
    #pragma unroll
    for (int r=0;r<8;++r) xe[r]=hu[r];
    #pragma unroll
    for (int r=0;r<4;++r) xe[8+r]=t29.u[r]; }
  {
    uint own[32];
    #pragma unroll
    for (int p=0;p<2;++p){
      float acc[32]; int jb2 = 64*wj + 32*p;
      #pragma unroll
      for (int j=0;j<32;++j) acc[j] = fs[FB_BSELF + jb2 + j];
      gpassR(acc, xe, wt, OFF_EGO + (long)jb2*24, 24, 3);
      #pragma unroll
      for (int t=0;t<16;++t){
        float a=acc[2*t], b=acc[2*t+1];
        a = a>=0.f? a : 0.01f*a;  b = b>=0.f? b : 0.01f*b;
        own[16*p+t] = packh2(a,b);
      }
    }
    uint* xw = (uint*)xa + (long)lane*68 + wj*32;
    #pragma unroll
    for (int t=0;t<32;++t) xw[t] = own[t];
  }
  __syncthreads();                                              // S2

  // ---- dyn: [128]->[64] ----
  float accW1[32];
  {
    float ef[32];
    #pragma unroll
    for (int j=0;j<32;++j) ef[j] = fs[FB_BDYN + jb + j];
    gpassL(ef, xrow, wt, OFF_DYN + (long)jb*128, 128, 16);
    __syncthreads();                                            // S3 (xa reads done)
    // feed ef into comb-W1 (k-block 0..63)
    uint* dst = (uint*)(pbrow + wj*32);
    #pragma unroll
    for (int t=0;t<16;++t) dst[t] = packh2(ef[2*t], ef[2*t+1]);
  }
  __syncthreads();                                              // S4
  #pragma unroll
  for (int j=0;j<32;++j) accW1[j] = fs[FB_CB1 + jb + j];
  gpassL(accW1, pbrow, wt, OFF_W1 + (long)jb*288, 288, 8);
  __syncthreads();                                              // S5

  // ---- lane MLP: [108(pad112)]->[64] relu -> [64]->[64] relu ----
  {
    float l1[32];
    #pragma unroll
    for (int j=0;j<32;++j) l1[j] = fs[FB_LB1 + jb + j];
    gpassL(l1, slp + 120, wt, OFF_L1 + (long)jb*112, 112, 14);
    uint* dst = (uint*)(pbrow + wj*32);
    #pragma unroll
    for (int t=0;t<16;++t) dst[t] = packh2(fmaxf(l1[2*t],0.f), fmaxf(l1[2*t+1],0.f));
  }
  __syncthreads();                                              // S6
  {
    float l2[32];
    #pragma unroll
    for (int j=0;j<32;++j) l2[j] = fs[FB_LB2 + jb + j];
    gpassL(l2, pbrow, wt, OFF_L2 + (long)jb*64, 64, 8);
    __syncthreads();                                            // S7
    uint* dst = (uint*)(pbrow + wj*32);
    #pragma unroll
    for (int t=0;t<16;++t) dst[t] = packh2(fmaxf(l2[2*t],0.f), fmaxf(l2[2*t+1],0.f));
  }
  __syncthreads();                                              // S8
  gpassL(accW1, pbrow, wt, OFF_W1 + (long)jb*288 + 192, 288, 8);  // lane block k192..255
  __syncthreads();                                              // S9

  // ---- GATs (star adjacency, collapsed). Per-lane scalar phase-1 ----
  float sx0=(float)slp[234], sy0=(float)slp[235], sz0=(float)slp[236];
  #pragma unroll
  for (int g=0; g<2; ++g){
    const int N = g? 9 : 13;
    const int xoff = g? 72 : 0;
    // attention-1 per head + aggregate (3-dim)
    float ag[3][3];
    #pragma unroll
    for (int hh=0; hh<3; ++hh){
      float u10=fs[FB_SU+g*18+0*9+hh*3+0], u11=fs[FB_SU+g*18+0*9+hh*3+1], u12=fs[FB_SU+g*18+0*9+hh*3+2];
      float u20=fs[FB_SU+g*18+1*9+hh*3+0], u21=fs[FB_SU+g*18+1*9+hh*3+1], u22=fs[FB_SU+g*18+1*9+hh*3+2];
      float s1v = u10*sx0 + u11*sy0 + u12*sz0;
      float sc[13]; float mx = -1e30f;
      #pragma unroll
      for (int n=0;n<13;++n){
        if (n>=N) break;
        float nx,ny,nz;
        if (n==0){ nx=sx0; ny=sy0; nz=sz0; }
        else { int b0 = xoff + (n-1)*6; nx=(float)slp[b0]; ny=(float)slp[b0+1]; nz=(float)slp[b0+2]; }
        float ev = lrelu(s1v + u20*nx + u21*ny + u22*nz, 0.2f);
        sc[n]=ev; mx = fmaxf(mx, ev);
      }
      float sum=0.f;
      #pragma unroll
      for (int n=0;n<13;++n){ if (n>=N) break; float w=__expf(sc[n]-mx); sc[n]=w; sum+=w; }
      float inv = 1.f/sum;
      float g0=0.f,g1=0.f,g2=0.f;
      #pragma unroll
      for (int n=0;n<13;++n){
        if (n>=N) break;
        float a = sc[n]*inv;
        float nx,ny,nz;
        if (n==0){ nx=sx0; ny=sy0; nz=sz0; }
        else { int b0 = xoff + (n-1)*6; nx=(float)slp[b0]; ny=(float)slp[b0+1]; nz=(float)slp[b0+2]; }
        g0 += a*nx; g1 += a*ny; g2 += a*nz;
      }
      ag[hh][0]=g0; ag[hh][1]=g1; ag[hh][2]=g2;
    }
    // x20 = elu(ag @ Wh'), x2X = elu(x0 @ Wh') -> LDS scratch (per-lane private)
    {
      const _Float16* wh = wt + OFF_WHX + g*192;
      uint* d20 = (uint*)xrow; uint* d2X = (uint*)(xrow + 48);
      #pragma unroll
      for (int t=0;t<24;++t){
        int j0=2*t, j1=2*t+1;
        int h0=j0>>4, h1=j1>>4;
        float wa0=(float)wh[j0*4], wa1=(float)wh[j0*4+1], wa2=(float)wh[j0*4+2];
        float wb0=(float)wh[j1*4], wb1=(float)wh[j1*4+1], wb2=(float)wh[j1*4+2];
        float v0 = eluf(ag[h0][0]*wa0 + ag[h0][1]*wa1 + ag[h0][2]*wa2);
        float v1 = eluf(ag[h1][0]*wb0 + ag[h1][1]*wb1 + ag[h1][2]*wb2);
        float x0v= eluf(sx0*wa0 + sy0*wa1 + sz0*wa2);
        float x1v= eluf(sx0*wb0 + sy0*wb1 + sz0*wb2);
        d20[t] = packh2(v0,v1); d2X[t] = packh2(x0v,x1v);
      }
    }
    // ho = x2 @ Wo (K=48), both branches share weights
    float a0[32], aX[32];
    #pragma unroll
    for (int j=0;j<32;++j){ a0[j]=0.f; aX[j]=0.f; }
    gpassL2(a0, aX, xrow, xrow+48, wt, OFF_WO + g*3072 + (long)jb*48, 48, 6);
    // attention-2: 2 distinct scores, multiplicity N-1 (cross-wave dot pieces)
    {
      float p1=0.f,p2=0.f,p3=0.f;
      const float* ao1 = fs + FB_AO + g*128 + jb;
      const float* ao2 = fs + FB_AO + g*128 + 64 + jb;
      #pragma unroll
      for (int j=0;j<32;++j){ float w1v=ao1[j], w2v=ao2[j];
        p1 += a0[j]*w1v; p2 += a0[j]*w2v; p3 += aX[j]*w2v; }
      pp[lane*8 + wj*4 + 0]=p1; pp[lane*8 + wj*4 + 1]=p2; pp[lane*8 + wj*4 + 2]=p3;
    }
    __syncthreads();                                            // S10/S13
    float q1 = pp[lane*8+0]+pp[lane*8+4];
    float q2 = pp[lane*8+1]+pp[lane*8+5];
    float q3 = pp[lane*8+2]+pp[lane*8+6];
    float e00 = lrelu(q1+q2, 0.2f), e0X = lrelu(q1+q3, 0.2f);
    float mm = fmaxf(e00,e0X);
    float w0 = __expf(e00-mm), wX = __expf(e0X-mm);
    float invden = 1.f/(w0 + (float)(N-1)*wX);
    float kX = (float)(N-1)*wX;
    // out_g[j] = elu((w0*a0 + (N-1)wX*aX)/den) -> exchange -> comb W1 block
    {
      uint* dst = (uint*)(pbrow + wj*32);
      #pragma unroll
      for (int t=0;t<16;++t){
        float va = (w0*a0[2*t]   + kX*aX[2*t]  )*invden;
        float vb = (w0*a0[2*t+1] + kX*aX[2*t+1])*invden;
        dst[t] = packh2(eluf(va), eluf(vb));
      }
    }
    __syncthreads();                                            // S11/S14
    gpassL(accW1, pbrow, wt, OFF_W1 + (long)jb*288 + (long)(8+8*g)*8, 288, 8);
    __syncthreads();                                            // S12/S15
  }

  // ---- comb: span block k256..287 = span[224,256) ----
  gpassL(accW1, slp + 224, wt, OFF_W1 + (long)jb*288 + 256, 288, 4);

  // ---- relu -> chid exchange -> W2 -> relu -> store ----
  {
    uint* dst = (uint*)(pbrow + wj*32);
    #pragma unroll
    for (int t=0;t<16;++t) dst[t] = packh2(fmaxf(accW1[2*t],0.f), fmaxf(accW1[2*t+1],0.f));
  }
  __syncthreads();                                              // S16
  {
    float o[32];
    #pragma unroll
    for (int j=0;j<32;++j) o[j] = fs[FB_CB2 + jb + j];
    gpassL(o, pbrow, wt, OFF_W2 + (long)jb*64, 64, 8);
    if (ge < Bn){
      float4* op = (float4*)(out + (long)ge*64 + jb);
      #pragma unroll
      for (int t=0;t<8;++t){
        float4 v; v.x=fmaxf(o[4*t],0.f); v.y=fmaxf(o[4*t+1],0.f);
        v.z=fmaxf(o[4*t+2],0.f); v.w=fmaxf(o[4*t+3],0.f);
        op[t]=v;
      }
    }
  }
}

extern "C" void kernel_launch(void* const* d_in, const int* in_sizes, int n_in,
                              void* d_out, int out_size, void* d_ws, size_t ws_size,
                              hipStream_t stream)
{
  const float* obs  =(const float*)d_in[0];
  const float* Wself=(const float*)d_in[1];  const float* bself=(const float*)d_in[2];
  const float* Wdyn =(const float*)d_in[3];  const float* bdyn =(const float*)d_in[4];
  const float* hWh  =(const float*)d_in[5];  const float* ha1  =(const float*)d_in[6];
  const float* ha2  =(const float*)d_in[7];  const float* hWo  =(const float*)d_in[8];
  const float* hao1 =(const float*)d_in[9];  const float* hao2 =(const float*)d_in[10];
  const float* cWh  =(const float*)d_in[11]; const float* ca1  =(const float*)d_in[12];
  const float* ca2  =(const float*)d_in[13]; const float* cWo  =(const float*)d_in[14];
  const float* cao1 =(const float*)d_in[15]; const float* cao2 =(const float*)d_in[16];
  const float* lW1  =(const float*)d_in[17]; const float* lb1  =(const float*)d_in[18];
  const float* lW2  =(const float*)d_in[19]; const float* lb2  =(const float*)d_in[20];
  const float* cmW1 =(const float*)d_in[21]; const float* cmb1 =(const float*)d_in[22];
  const float* cmW2 =(const float*)d_in[23]; const float* cmb2 =(const float*)d_in[24];

  int Bn = in_sizes[0] / ROW;
  _Float16* wt = (_Float16*)d_ws;
  float* out = (float*)d_out;

  k_prep<<<64,256,0,stream>>>(Wself,Wdyn,lW1,lW2,hWh,cWh,hWo,cWo,ha1,ha2,ca1,ca2,
                              hao1,hao2,cao1,cao2,bself,bdyn,lb1,lb2,cmb1,cmb2,wt);
  k_prep2<<<64,256,0,stream>>>(cmW1,cmW2,wt);
  int blocks = (Bn + 63)/64;
  k_main<<<blocks,128,0,stream>>>(obs,wt,out,Bn);
}

// Round 4
// 422.853 us; speedup vs baseline: 1.5831x; 1.5054x over previous
//
#include <hip/hip_runtime.h>
#include <math.h>

#define ROW 2064   // 6*344 floats per obs row
#define OS  344

typedef _Float16 h2 __attribute__((ext_vector_type(2)));
typedef _Float16 h8 __attribute__((ext_vector_type(8)));

// fp16 weight blob layout (offsets in f16 units), identical to round 3.
#define OFF_EGO 0        // 128 x 24
#define OFF_DYN 3072     // 64 x 128
#define OFF_L1  11264    // 64 x 112
#define OFF_L2  18432    // 64 x 64
#define OFF_WHX 22528    // 2 x 48 x 4
#define OFF_WO  22912    // 2 x 64 x 48
#define OFF_W1  29056    // 64 x 288 (k: ef64, hdv64, cav64, lane64, span[224..256))
#define OFF_W2  47488    // 64 x 64
#define WT_F16  51584
#define FB_BSELF 0
#define FB_BDYN 128
#define FB_LB1 192
#define FB_LB2 256
#define FB_CB1 320
#define FB_CB2 384
#define FB_SU  448   // [g][w][h][f] : 36
#define FB_AO  484   // [g][w][64]   : 256
#define FS_TOT 740

union U4 { uint4 q; h2 p[8]; };
union U1 { uint u; h2 h; };

__device__ __forceinline__ float fd(h2 a, h2 b, float c){
#if __has_builtin(__builtin_amdgcn_fdot2)
  return __builtin_amdgcn_fdot2(a,b,c,false);
#else
  return c + (float)a.x*(float)b.x + (float)a.y*(float)b.y;
#endif
}
__device__ __forceinline__ float lrelu(float x,float s){ return x>=0.f? x : s*x; }
__device__ __forceinline__ float eluf(float x){ return x>0.f? x : expm1f(x); }
__device__ __forceinline__ uint packh2(float a,float b){ U1 u; u.h=(h2){(_Float16)a,(_Float16)b}; return u.u; }

__device__ __forceinline__ int span_to_comb(int sp){
  switch(sp){ case 228: return 256; case 229: return 257; case 230: return 260; case 231: return 261;
    case 232: return 264; case 233: return 265; case 247: return 258; case 248: return 259;
    case 249: return 262; case 250: return 263; case 251: return 267; case 252: return 268;
    case 253: return 266; default: return -1; }
}

// ======================= prologue: weight repack fp32 -> fp16 blob =======================
__global__ void k_prep(const float* __restrict__ Wself, const float* __restrict__ Wdyn,
                       const float* __restrict__ lW1, const float* __restrict__ lW2,
                       const float* __restrict__ hWh, const float* __restrict__ cWh,
                       const float* __restrict__ hWo, const float* __restrict__ cWo,
                       const float* __restrict__ ha1, const float* __restrict__ ha2,
                       const float* __restrict__ ca1, const float* __restrict__ ca2,
                       const float* __restrict__ hao1, const float* __restrict__ hao2,
                       const float* __restrict__ cao1, const float* __restrict__ cao2,
                       const float* __restrict__ bself, const float* __restrict__ bdyn,
                       const float* __restrict__ lb1, const float* __restrict__ lb2,
                       const float* __restrict__ cb1, const float* __restrict__ cb2,
                       _Float16* __restrict__ wt)
{
  int gid = blockIdx.x*blockDim.x + threadIdx.x;
  int nth = gridDim.x*blockDim.x;
  for (int idx = gid; idx < OFF_W1; idx += nth){
    float v = 0.f;
    if (idx < OFF_DYN){ int l=idx; int j=l/24, k=l%24;
      if (k<16){ int s=k>>2, c=k&3; if (c<3) v = Wself[(s*3+c)*128 + j]; }
      else { int sp = 232 + (k-16); if (sp>=234 && sp<=236) v = Wself[(12+(sp-234))*128 + j]; }
    } else if (idx < OFF_L1){ int l=idx-OFF_DYN; int j=l>>7, k=l&127; v = Wdyn[k*64+j]; }
    else if (idx < OFF_L2){ int l=idx-OFF_L1; int j=l/112, k=l%112; if (k<108) v = lW1[k*64+j]; }
    else if (idx < OFF_WHX){ int l=idx-OFF_L2; int j=l>>6, k=l&63; v = lW2[k*64+j]; }
    else if (idx < OFF_WO){ int l=idx-OFF_WHX; int g=l/192; l-=g*192; int j=l>>2, k=l&3;
      const float* Wh = g? cWh : hWh; int hh=j>>4, o=j&15; if (k<3) v = Wh[hh*48 + k*16 + o]; }
    else { int l=idx-OFF_WO; int g=l/3072; l-=g*3072; int j=l/48, k=l%48;
      const float* Wo = g? cWo : hWo; v = Wo[k*64+j]; }
    wt[idx] = (_Float16)v;
  }
  float* fso = (float*)(wt + WT_F16);
  for (int i = gid; i < FS_TOT; i += nth){
    float v=0.f;
    if (i<128) v = bself[i];
    else if (i<192) v = bdyn[i-128];
    else if (i<256) v = lb1[i-192];
    else if (i<320) v = lb2[i-256];
    else if (i<384) v = cb1[i-320];
    else if (i<448) v = cb2[i-384];
    else if (i<484){ int t=i-448; int g=t/18, w=(t%18)/9, hh=(t%9)/3, f=t%3;
      const float* A = g? (w? ca2:ca1) : (w? ha2:ha1);
      const float* WH = g? cWh : hWh; v=0.f;
      for (int o=0;o<16;++o) v += WH[hh*48+f*16+o]*A[hh*16+o]; }
    else { int t=i-484; int g=t>>7, w=(t>>6)&1, j=t&63;
      const float* A = g? (w?cao2:cao1) : (w?hao2:hao1); v = A[j]; }
    fso[i]=v;
  }
}

__global__ void k_prep2(const float* __restrict__ cmW1, const float* __restrict__ cmW2,
                        _Float16* __restrict__ wt)
{
  int gid = blockIdx.x*blockDim.x + threadIdx.x;
  int nth = gridDim.x*blockDim.x;
  for (int idx = gid + OFF_W1; idx < WT_F16; idx += nth){
    float v = 0.f;
    if (idx < OFF_W2){ int l=idx-OFF_W1; int j=l/288, k=l%288;
      int r = (k<256) ? k : span_to_comb(224 + (k-256));
      if (r>=0) v = cmW1[r*64 + j];
    } else { int l=idx-OFF_W2; int j=l>>6, k=l&63; v = cmW2[k*64+j]; }
    wt[idx] = (_Float16)v;
  }
}

// ======================= gpass helpers (8 wave-uniform cols) =======================
__device__ __forceinline__ float dot8u(uint a,uint b,uint c,uint d, const U4& q, float t){
  U1 u; u.u=a; t=fd(u.h,q.p[0],t); u.u=b; t=fd(u.h,q.p[1],t);
  u.u=c; t=fd(u.h,q.p[2],t); u.u=d; t=fd(u.h,q.p[3],t); return t;
}

// x from transposed LDS: chunk c at xl + c*512 f16 (lane*16B contiguous -> conflict-free)
__device__ __forceinline__ void gpass8(float acc[8], const _Float16* xl,
    const _Float16* __restrict__ wt, long wbase, int KP, int C){
  #pragma unroll 2
  for (int c=0;c<C;++c){
    union{h8 v; uint u[4];} x; x.v = *(const h8*)(xl + (long)c*512);
    #pragma unroll
    for (int j=0;j<8;++j){
      U4 q = *(const U4*)(wt + wbase + (long)j*KP + c*8);
      acc[j] = dot8u(x.u[0],x.u[1],x.u[2],x.u[3],q,acc[j]);
    }
  }
}

__device__ __forceinline__ void put_piece(_Float16* pbase, int wj, int lane, const float* v8){
  uint4 q; q.x=packh2(v8[0],v8[1]); q.y=packh2(v8[2],v8[3]);
  q.z=packh2(v8[4],v8[5]); q.w=packh2(v8[6],v8[7]);
  *(uint4*)(pbase + wj*512 + lane*8) = q;
}

// ======================= GAT phase-1 (per (g,head) wave) =======================
template<int N>
__device__ __forceinline__ void gat_phase1(const float* __restrict__ fs,
    const _Float16* __restrict__ wt, const float* __restrict__ nod,
    int g, int hh, _Float16* scr, int lane)
{
  const int xoff = (N==13)? 0 : 72;
  float sx0=nod[234], sy0=nod[235], sz0=nod[236];
  float u10=fs[FB_SU+g*18+hh*3+0], u11=fs[FB_SU+g*18+hh*3+1], u12=fs[FB_SU+g*18+hh*3+2];
  float u20=fs[FB_SU+g*18+9+hh*3+0], u21=fs[FB_SU+g*18+9+hh*3+1], u22=fs[FB_SU+g*18+9+hh*3+2];
  float s1v = u10*sx0 + u11*sy0 + u12*sz0;
  float sc[N]; float mx = -1e30f;
  #pragma unroll
  for (int n=0;n<N;++n){
    float nx,ny,nz;
    if (n==0){ nx=sx0; ny=sy0; nz=sz0; }
    else { int b0=xoff+(n-1)*6; nx=nod[b0]; ny=nod[b0+1]; nz=nod[b0+2]; }
    float ev = lrelu(s1v + u20*nx + u21*ny + u22*nz, 0.2f);
    sc[n]=ev; mx=fmaxf(mx,ev);
  }
  float sum=0.f;
  #pragma unroll
  for (int n=0;n<N;++n){ float w=__expf(sc[n]-mx); sc[n]=w; sum+=w; }
  float inv = 1.f/sum;
  float g0=0.f,g1=0.f,g2=0.f;
  #pragma unroll
  for (int n=0;n<N;++n){
    float a = sc[n]*inv; float nx,ny,nz;
    if (n==0){ nx=sx0; ny=sy0; nz=sz0; }
    else { int b0=xoff+(n-1)*6; nx=nod[b0]; ny=nod[b0+1]; nz=nod[b0+2]; }
    g0 += a*nx; g1 += a*ny; g2 += a*nz;
  }
  // x20/x2X outputs for this head: cols hh*16..hh*16+15
  const _Float16* wh = wt + OFF_WHX + g*192 + (hh*16)*4;
  uint o20[8], o2X[8];
  #pragma unroll
  for (int t=0;t<8;++t){
    float wa0=(float)wh[(2*t)*4],   wa1=(float)wh[(2*t)*4+1],   wa2=(float)wh[(2*t)*4+2];
    float wb0=(float)wh[(2*t+1)*4], wb1=(float)wh[(2*t+1)*4+1], wb2=(float)wh[(2*t+1)*4+2];
    float v0 = eluf(g0*wa0 + g1*wa1 + g2*wa2);
    float v1 = eluf(g0*wb0 + g1*wb1 + g2*wb2);
    float xv0= eluf(sx0*wa0 + sy0*wa1 + sz0*wa2);
    float xv1= eluf(sx0*wb0 + sy0*wb1 + sz0*wb2);
    o20[t]=packh2(v0,v1); o2X[t]=packh2(xv0,xv1);
  }
  int c20 = (g*2)*6 + 2*hh, c2X = (g*2+1)*6 + 2*hh;
  *(uint4*)(scr + (long)c20*512 + lane*8)     = make_uint4(o20[0],o20[1],o20[2],o20[3]);
  *(uint4*)(scr + (long)(c20+1)*512 + lane*8) = make_uint4(o20[4],o20[5],o20[6],o20[7]);
  *(uint4*)(scr + (long)c2X*512 + lane*8)     = make_uint4(o2X[0],o2X[1],o2X[2],o2X[3]);
  *(uint4*)(scr + (long)(c2X+1)*512 + lane*8) = make_uint4(o2X[4],o2X[5],o2X[6],o2X[7]);
}

// ======================= main fused kernel =======================
// 512 thr = 8 waves; wave wj owns cols [8wj,8wj+8); lane = example (64/block).
__global__ __launch_bounds__(512,4) void k_main(const float* __restrict__ obs,
    const _Float16* __restrict__ wt, float* __restrict__ out, int Bn)
{
  __shared__ __align__(16) unsigned char smem[60416];
  _Float16* slt = (_Float16*)smem;              // 17 chunks: span f16 pos [120..256)
  _Float16* scr = (_Float16*)(smem + 17408);    // 24 chunks: x128 exchange / GAT x20,x2X
  float*    pp  = (float*)(smem + 41984);       // [8 wave][64 lane][5] f32 (stride-5: conflict-free)
  _Float16* pbx = (_Float16*)(smem + 52224);    // 8 chunks: 64-col piece exchange

  const float* fs = (const float*)(wt + WT_F16);
  int wj   = __builtin_amdgcn_readfirstlane((int)(threadIdx.x >> 6));
  int lane = threadIdx.x & 63;
  int jb   = 8*wj;
  int e0   = blockIdx.x*64;
  int ge   = e0 + lane; int gec = ge < Bn ? ge : Bn-1;
  const float* nod   = obs + (long)gec*ROW + 5*OS;
  const float* myrow = obs + (long)gec*ROW;

  // ---- stage span [5OS+120, 5OS+256) into transposed LDS (coalesced global reads) ----
  for (int t=wj; t<64; t+=8){
    int gx = e0 + t; if (gx >= Bn) gx = Bn-1;
    float4 v = *(const float4*)(obs + (long)gx*ROW + 5*OS + 4*lane);
    if (lane >= 30){
      uint2 w; w.x = packh2(v.x,v.y); w.y = packh2(v.z,v.w);
      *(uint2*)(slt + (long)((lane>>1)-15)*512 + t*8 + (lane&1)*4) = w;
    }
  }
  // hist (own example): 4 steps x 2 float2 -> 8 packed uints
  uint xe[12];
  #pragma unroll
  for (int s=0;s<4;++s){
    float2 ab = *(const float2*)(myrow + (s+1)*OS + 234);
    float2 cd = *(const float2*)(myrow + (s+1)*OS + 236);
    xe[2*s]=packh2(ab.x,ab.y); xe[2*s+1]=packh2(cd.x,cd.y);
  }
  __syncthreads();                                              // S1
  { union{h8 v; uint u[4];} t29; t29.v = *(const h8*)(slt + 14*512 + lane*8);  // span[232..240)
    xe[8]=t29.u[0]; xe[9]=t29.u[1]; xe[10]=t29.u[2]; xe[11]=t29.u[3]; }

  // ---- ego: [24]->[128], double leaky(0.1); 16 cols/wave in 2 passes ----
  {
    uint own[8];
    #pragma unroll
    for (int p=0;p<2;++p){
      float acc[8]; int cb = 16*wj + 8*p;
      #pragma unroll
      for (int j=0;j<8;++j) acc[j] = fs[FB_BSELF + cb + j];
      #pragma unroll
      for (int c=0;c<3;++c){
        uint a=xe[4*c], b=xe[4*c+1], cc2=xe[4*c+2], d=xe[4*c+3];
        #pragma unroll
        for (int j=0;j<8;++j){
          U4 q = *(const U4*)(wt + OFF_EGO + (long)(cb+j)*24 + c*8);
          acc[j] = dot8u(a,b,cc2,d,q,acc[j]);
        }
      }
      #pragma unroll
      for (int t=0;t<4;++t){
        float a=acc[2*t], b=acc[2*t+1];
        a = a>=0.f? a : 0.01f*a;  b = b>=0.f? b : 0.01f*b;
        own[4*p+t] = packh2(a,b);
      }
    }
    *(uint4*)(scr + (long)(2*wj)*512 + lane*8)   = make_uint4(own[0],own[1],own[2],own[3]);
    *(uint4*)(scr + (long)(2*wj+1)*512 + lane*8) = make_uint4(own[4],own[5],own[6],own[7]);
  }
  __syncthreads();                                              // S2

  // ---- dyn: [128]->[64] ----
  float accW1[8];
  {
    float ef[8];
    #pragma unroll
    for (int j=0;j<8;++j) ef[j] = fs[FB_BDYN + jb + j];
    gpass8(ef, scr + lane*8, wt, OFF_DYN + (long)jb*128, 128, 16);
    __syncthreads();                                            // S3 (scr/xa reads done)
    put_piece(pbx, wj, lane, ef);
  }
  __syncthreads();                                              // S4
  #pragma unroll
  for (int j=0;j<8;++j) accW1[j] = fs[FB_CB1 + jb + j];
  gpass8(accW1, pbx + lane*8, wt, OFF_W1 + (long)jb*288, 288, 8);
  __syncthreads();                                              // S5

  // ---- lane MLP: [108(pad112)]->[64] relu -> [64]->[64] relu ----
  {
    float l1[8];
    #pragma unroll
    for (int j=0;j<8;++j) l1[j] = fs[FB_LB1 + jb + j];
    gpass8(l1, slt + lane*8, wt, OFF_L1 + (long)jb*112, 112, 14);
    #pragma unroll
    for (int j=0;j<8;++j) l1[j] = fmaxf(l1[j],0.f);
    put_piece(pbx, wj, lane, l1);
  }
  __syncthreads();                                              // S6
  {
    float l2[8];
    #pragma unroll
    for (int j=0;j<8;++j) l2[j] = fs[FB_LB2 + jb + j];
    gpass8(l2, pbx + lane*8, wt, OFF_L2 + (long)jb*64, 64, 8);
    __syncthreads();                                            // S7
    #pragma unroll
    for (int j=0;j<8;++j) l2[j] = fmaxf(l2[j],0.f);
    put_piece(pbx, wj, lane, l2);
  }
  __syncthreads();                                              // S8
  gpass8(accW1, pbx + lane*8, wt, OFF_W1 + (long)jb*288 + 192, 288, 8);
  __syncthreads();                                              // S9

  // ---- GAT phase-1: one wave per (g,head); waves 3,7 idle ----
  if (wj < 3)             gat_phase1<13>(fs, wt, nod, 0, wj,   scr, lane);
  else if (wj>=4 && wj<7) gat_phase1<9> (fs, wt, nod, 1, wj-4, scr, lane);
  __syncthreads();                                              // S10

  // ---- GAT WO + attention-2 + W1 blocks ----
  for (int g=0; g<2; ++g){
    const int N = g? 9 : 13;
    float a0[8], aX[8];
    #pragma unroll
    for (int j=0;j<8;++j){ a0[j]=0.f; aX[j]=0.f; }
    long wb = OFF_WO + g*3072 + (long)jb*48;
    #pragma unroll 2
    for (int c=0;c<6;++c){
      union{h8 v; uint u[4];} x0, x1;
      x0.v = *(const h8*)(scr + (long)((g*2)*6+c)*512 + lane*8);
      x1.v = *(const h8*)(scr + (long)((g*2+1)*6+c)*512 + lane*8);
      #pragma unroll
      for (int j=0;j<8;++j){
        U4 q = *(const U4*)(wt + wb + (long)j*48 + c*8);
        a0[j] = dot8u(x0.u[0],x0.u[1],x0.u[2],x0.u[3],q,a0[j]);
        aX[j] = dot8u(x1.u[0],x1.u[1],x1.u[2],x1.u[3],q,aX[j]);
      }
    }
    float p1=0.f,p2=0.f,p3=0.f;
    #pragma unroll
    for (int j=0;j<8;++j){
      float w1v=fs[FB_AO + g*128 + jb + j], w2v=fs[FB_AO + g*128 + 64 + jb + j];
      p1 += a0[j]*w1v; p2 += a0[j]*w2v; p3 += aX[j]*w2v;
    }
    { float* pr = pp + (long)(wj*64+lane)*5; pr[0]=p1; pr[1]=p2; pr[2]=p3; }
    __syncthreads();                                            // S11/S14
    float q1=0.f,q2=0.f,q3=0.f;
    #pragma unroll
    for (int w=0;w<8;++w){ const float* pr = pp + (long)(w*64+lane)*5;
      q1+=pr[0]; q2+=pr[1]; q3+=pr[2]; }
    float e00=lrelu(q1+q2,0.2f), e0X=lrelu(q1+q3,0.2f);
    float mm=fmaxf(e00,e0X);
    float w0=__expf(e00-mm), wX=__expf(e0X-mm);
    float invden = 1.f/(w0 + (float)(N-1)*wX);
    float kX = (float)(N-1)*wX*invden; w0 *= invden;
    float og[8];
    #pragma unroll
    for (int j=0;j<8;++j) og[j] = eluf(w0*a0[j] + kX*aX[j]);
    put_piece(pbx, wj, lane, og);
    __syncthreads();                                            // S12/S15
    gpass8(accW1, pbx + lane*8, wt, OFF_W1 + (long)jb*288 + 64 + 64*g, 288, 8);
    __syncthreads();                                            // S13/S16
  }

  // ---- comb span block: span[224..256) = slt chunks 13..16, W1 k256..287 ----
  gpass8(accW1, slt + 13*512 + lane*8, wt, OFF_W1 + (long)jb*288 + 256, 288, 4);

  // ---- relu -> chid piece -> W2 -> relu -> store ----
  {
    float ch[8];
    #pragma unroll
    for (int j=0;j<8;++j) ch[j] = fmaxf(accW1[j],0.f);
    put_piece(pbx, wj, lane, ch);
  }
  __syncthreads();                                              // S17
  {
    float o[8];
    #pragma unroll
    for (int j=0;j<8;++j) o[j] = fs[FB_CB2 + jb + j];
    gpass8(o, pbx + lane*8, wt, OFF_W2 + (long)jb*64, 64, 8);
    if (ge < Bn){
      float4 v0, v1;
      v0.x=fmaxf(o[0],0.f); v0.y=fmaxf(o[1],0.f); v0.z=fmaxf(o[2],0.f); v0.w=fmaxf(o[3],0.f);
      v1.x=fmaxf(o[4],0.f); v1.y=fmaxf(o[5],0.f); v1.z=fmaxf(o[6],0.f); v1.w=fmaxf(o[7],0.f);
      *(float4*)(out + (long)ge*64 + jb)     = v0;
      *(float4*)(out + (long)ge*64 + jb + 4) = v1;
    }
  }
}

extern "C" void kernel_launch(void* const* d_in, const int* in_sizes, int n_in,
                              void* d_out, int out_size, void* d_ws, size_t ws_size,
                              hipStream_t stream)
{
  const float* obs  =(const float*)d_in[0];
  const float* Wself=(const float*)d_in[1];  const float* bself=(const float*)d_in[2];
  const float* Wdyn =(const float*)d_in[3];  const float* bdyn =(const float*)d_in[4];
  const float* hWh  =(const float*)d_in[5];  const float* ha1  =(const float*)d_in[6];
  const float* ha2  =(const float*)d_in[7];  const float* hWo  =(const float*)d_in[8];
  const float* hao1 =(const float*)d_in[9];  const float* hao2 =(const float*)d_in[10];
  const float* cWh  =(const float*)d_in[11]; const float* ca1  =(const float*)d_in[12];
  const float* ca2  =(const float*)d_in[13]; const float* cWo  =(const float*)d_in[14];
  const float* cao1 =(const float*)d_in[15]; const float* cao2 =(const float*)d_in[16];
  const float* lW1  =(const float*)d_in[17]; const float* lb1  =(const float*)d_in[18];
  const float* lW2  =(const float*)d_in[19]; const float* lb2  =(const float*)d_in[20];
  const float* cmW1 =(const float*)d_in[21]; const float* cmb1 =(const float*)d_in[22];
  const float* cmW2 =(const float*)d_in[23]; const float* cmb2 =(const float*)d_in[24];

  int Bn = in_sizes[0] / ROW;
  _Float16* wt = (_Float16*)d_ws;
  float* out = (float*)d_out;

  k_prep<<<64,256,0,stream>>>(Wself,Wdyn,lW1,lW2,hWh,cWh,hWo,cWo,ha1,ha2,ca1,ca2,
                              hao1,hao2,cao1,cao2,bself,bdyn,lb1,lb2,cmb1,cmb2,wt);
  k_prep2<<<64,256,0,stream>>>(cmW1,cmW2,wt);
  int blocks = (Bn + 63)/64;
  k_main<<<blocks,512,0,stream>>>(obs,wt,out,Bn);
}